// Round 11
// baseline (36.181 us; speedup 1.0000x reference)
//
#include <hip/hip_runtime.h>
#include <hip/hip_bf16.h>
#include <math.h>

// Problem constants (DeepFM)
#define BTOT   16384
#define NF     26
#define VOCAB  100000
#define EDIM   16
#define DD     13
#define KPAD   448      // 429 padded to 14*32
#define KREAL  429
#define N1     256
#define N2     128
#define APAD   456      // A tile row stride (448+8)
#define H2PAD  264      // H2 tile row stride (256+8)

typedef __attribute__((ext_vector_type(8))) short bf16x8;
typedef __attribute__((ext_vector_type(4))) short bf16x4;
typedef __attribute__((ext_vector_type(4))) float f32x4;

static __device__ __forceinline__ bf16x8 ldb8(const __hip_bfloat16* p) {
  return *reinterpret_cast<const bf16x8*>(p);
}
static __device__ __forceinline__ short f2bf(float f) {
  __hip_bfloat16 h = __float2bfloat16(f);
  return *reinterpret_cast<short*>(&h);
}

// Barrier that does NOT drain vmcnt: LDS visibility only. In-flight global
// (gather prefetch) loads survive across it.
#define LGKM_BAR() do {                                   \
  asm volatile("s_waitcnt lgkmcnt(0)" ::: "memory");      \
  __builtin_amdgcn_s_barrier();                           \
  asm volatile("" ::: "memory");                          \
} while (0)

// ---------------------------------------------------------------------------
// Kernel 1: repack weights -> bf16 B-fragment layout (proven R4 version).
// ---------------------------------------------------------------------------
__global__ __launch_bounds__(512) void convert_weights(
    const float* __restrict__ W1, const float* __restrict__ W2,
    __hip_bfloat16* __restrict__ W1f, __hip_bfloat16* __restrict__ W2f) {
  const int bid = blockIdx.x;
  const int k = threadIdx.x;
  if (bid < 256) {
    const int n = bid;
    if (k < 448) {
      float v = (k < KREAL) ? W1[(size_t)n * KREAL + k] : 0.f;
      W1f[(((size_t)(k >> 3)) * N1 + n) * 8 + (k & 7)] = __float2bfloat16(v);
    }
  } else {
    const int n = bid - 256;
    if (k < 256) {
      float v = W2[(size_t)n * 256 + k];
      W2f[(((size_t)(k >> 3)) * N2 + n) * 8 + (k & 7)] = __float2bfloat16(v);
    }
  }
}

// ---------------------------------------------------------------------------
// Gather issue: fire this tile's fm/lin loads (results land later; compiler
// inserts vmcnt waits at first use in build_tile).
// Thread map (32 thr/sample): q=sub&3 (e-quarter), g=sub>>2 (fields g+8i).
// ---------------------------------------------------------------------------
__device__ __forceinline__ void gather_issue(
    int g, int q, const int idxs[4],
    const float* __restrict__ fmW, const float* __restrict__ linW,
    f32x4 v[4], float& lin) {
  lin = 0.f;
#pragma unroll
  for (int i = 0; i < 4; ++i) {
    const int f = g + 8 * i;
    if (f < NF) {
      v[i] = *reinterpret_cast<const f32x4*>(
          fmW + ((size_t)f * VOCAB + idxs[i]) * EDIM + q * 4);
      if (q == i)                     // each field's lin value loaded once
        lin = linW[(size_t)f * VOCAB + idxs[i]];
    }
  }
}

// Consume gathered registers: FM sums + A-tile LDS writes + fm-logit.
__device__ __forceinline__ void build_tile(
    int s, int sub, int q, int g, const f32x4 v[4], float lin, float xd,
    const float* __restrict__ denseW, const float* __restrict__ denseB,
    __hip_bfloat16 (*Ash)[APAD], float* __restrict__ fml_slot) {
  f32x4 sum = (f32x4){0.f, 0.f, 0.f, 0.f};
  f32x4 sumsq = (f32x4){0.f, 0.f, 0.f, 0.f};
  float part = lin;
#pragma unroll
  for (int i = 0; i < 4; ++i) {
    const int f = g + 8 * i;
    if (f < NF) {
      f32x4 vv = v[i];
      sum += vv;
      sumsq += vv * vv;
      bf16x4 pk;
      pk[0] = f2bf(vv[0]); pk[1] = f2bf(vv[1]);
      pk[2] = f2bf(vv[2]); pk[3] = f2bf(vv[3]);
      *reinterpret_cast<bf16x4*>(&Ash[s][f * EDIM + q * 4]) = pk;
    }
  }
#pragma unroll
  for (int off = 4; off <= 16; off <<= 1) {
#pragma unroll
    for (int c = 0; c < 4; ++c) {
      sum[c] += __shfl_xor(sum[c], off);
      sumsq[c] += __shfl_xor(sumsq[c], off);
    }
  }
  if (g == 0) {                       // each e-quarter counted once
    f32x4 c4 = sum * sum - sumsq;
    part += 0.5f * (c4[0] + c4[1] + c4[2] + c4[3]);
  }
  Ash[s][416 + sub] = __float2bfloat16(xd);   // dense + zero pad (sub 0..31)
  if (sub < DD) part += xd * denseW[sub];
#pragma unroll
  for (int off = 1; off < 32; off <<= 1)
    part += __shfl_xor(part, off);
  if (sub == 0) fml_slot[s] = part + denseB[0];
}

// GEMM1 over a 32-row tile: 16 waves x 16 cols; 2 m-tiles.
__device__ __forceinline__ void gemm1_32(
    int wave, int lr, int kg,
    const __hip_bfloat16 (*Ash)[APAD], __hip_bfloat16 (*H2sh)[H2PAD],
    const __hip_bfloat16* __restrict__ W1f, const float* __restrict__ bias1) {
  const int n0 = wave * 16;
  f32x4 acc[2];
  acc[0] = (f32x4){0.f, 0.f, 0.f, 0.f};
  acc[1] = (f32x4){0.f, 0.f, 0.f, 0.f};
#pragma unroll
  for (int kt = 0; kt < KPAD / 32; ++kt) {
    const int kbase = kt * 32 + kg * 8;
    bf16x8 bf = ldb8(W1f + ((size_t)(kbase >> 3) * N1 + n0 + lr) * 8);
#pragma unroll
    for (int mt = 0; mt < 2; ++mt) {
      bf16x8 af = *reinterpret_cast<const bf16x8*>(&Ash[mt * 16 + lr][kbase]);
      acc[mt] = __builtin_amdgcn_mfma_f32_16x16x32_bf16(af, bf, acc[mt], 0, 0, 0);
    }
  }
  const int col = n0 + lr;
  const float bias = bias1[col];
#pragma unroll
  for (int mt = 0; mt < 2; ++mt) {
#pragma unroll
    for (int r = 0; r < 4; ++r) {
      float v = acc[mt][r] + bias;
      v = v > 0.f ? v : 0.f;
      H2sh[mt * 16 + kg * 4 + r][col] = __float2bfloat16(v);
    }
  }
}

// GEMM2 over a 32-row tile: wave = (col-slice c, m-half h); + Wout dot.
__device__ __forceinline__ void gemm2_32(
    int wave, int lr, int kg,
    const __hip_bfloat16 (*H2sh)[H2PAD], float (*redsh)[8],
    const __hip_bfloat16* __restrict__ W2f, const float* __restrict__ bias2,
    const float* __restrict__ Wout) {
  const int c = wave & 7;
  const int h = wave >> 3;
  const int n0 = c * 16;
  f32x4 acc = (f32x4){0.f, 0.f, 0.f, 0.f};
#pragma unroll
  for (int kt = 0; kt < N1 / 32; ++kt) {
    const int kbase = kt * 32 + kg * 8;
    bf16x8 bf = ldb8(W2f + ((size_t)(kbase >> 3) * N2 + n0 + lr) * 8);
    bf16x8 af = *reinterpret_cast<const bf16x8*>(&H2sh[h * 16 + lr][kbase]);
    acc = __builtin_amdgcn_mfma_f32_16x16x32_bf16(af, bf, acc, 0, 0, 0);
  }
  const float w0 = Wout[n0 + lr];
  const float bb0 = bias2[n0 + lr];
#pragma unroll
  for (int r = 0; r < 4; ++r) {
    float v = acc[r] + bb0;
    v = v > 0.f ? v : 0.f;
    v *= w0;
#pragma unroll
    for (int off = 1; off < 16; off <<= 1)
      v += __shfl_xor(v, off);
    if (lr == 0) redsh[h * 16 + kg * 4 + r][c] = v;
  }
}

// ---------------------------------------------------------------------------
// Fused kernel: 1024 thr = 16 waves, grid 256; block = 2 tiles x 32 samples.
// Tile1's gather loads are issued in the prologue and stay in flight across
// tile0's GEMMs (lgkm-only barriers) — T14 async-STAGE across tiles.
// ---------------------------------------------------------------------------
__global__ __launch_bounds__(1024, 4) void deepfm_fused(
    const int* __restrict__ Xs, const float* __restrict__ Xd,
    const float* __restrict__ linW, const float* __restrict__ fmW,
    const float* __restrict__ denseW, const float* __restrict__ denseB,
    const __hip_bfloat16* __restrict__ W1f, const float* __restrict__ bias1,
    const __hip_bfloat16* __restrict__ W2f, const float* __restrict__ bias2,
    const float* __restrict__ Wout, float* __restrict__ out) {

  __shared__ __hip_bfloat16 Ash[32][APAD];
  __shared__ __hip_bfloat16 H2sh[32][H2PAD];
  __shared__ float fmlsh[64];
  __shared__ float redsh[32][8];

  const int tid = threadIdx.x;
  const int wave = tid >> 6;
  const int lane = tid & 63;
  const int lr = lane & 15;
  const int kg = lane >> 4;
  const size_t blk0 = (size_t)blockIdx.x * 64;

  const int s   = tid >> 5;           // local sample 0..31
  const int sub = tid & 31;
  const int q   = sub & 3;
  const int g   = sub >> 2;
  const size_t sb0 = blk0 + s;
  const size_t sb1 = sb0 + 32;

  // ---- prologue: issue indices for both tiles, then both gather sets ----
  const int* xr0 = Xs + sb0 * NF;
  const int* xr1 = Xs + sb1 * NF;
  int idx0[4], idx1[4];
#pragma unroll
  for (int i = 0; i < 4; ++i) {
    const int f = g + 8 * i;
    idx0[i] = (f < NF) ? xr0[f] : 0;
    idx1[i] = (f < NF) ? xr1[f] : 0;
  }
  float xd0 = (sub < DD) ? Xd[sb0 * DD + sub] : 0.f;
  float xd1 = (sub < DD) ? Xd[sb1 * DD + sub] : 0.f;

  f32x4 v0[4]; float lin0;
  gather_issue(g, q, idx0, fmW, linW, v0, lin0);
  f32x4 v1[4]; float lin1;
  gather_issue(g, q, idx1, fmW, linW, v1, lin1);

  // ---- tile 0 build (waits v0; v1 stays in flight) ----
  build_tile(s, sub, q, g, v0, lin0, xd0, denseW, denseB, Ash, fmlsh);
  LGKM_BAR();                                   // #1 — v1 survives

  gemm1_32(wave, lr, kg, Ash, H2sh, W1f, bias1);
  LGKM_BAR();                                   // #2 — v1 survives

  gemm2_32(wave, lr, kg, H2sh, redsh, W2f, bias2, Wout);
  LGKM_BAR();                                   // #3 — v1 survives

  // ---- out(0) + tile 1 build (consumes v1 here) ----
  if (tid < 32) {
    float t = 0.f;
#pragma unroll
    for (int w = 0; w < 8; ++w) t += redsh[tid][w];
    float x = fmlsh[tid] + t;
    out[blk0 + tid] = 1.f / (1.f + expf(-x));
  }
  build_tile(s, sub, q, g, v1, lin1, xd1, denseW, denseB, Ash, fmlsh + 32);
  __syncthreads();                              // #4

  gemm1_32(wave, lr, kg, Ash, H2sh, W1f, bias1);
  __syncthreads();                              // #5

  gemm2_32(wave, lr, kg, H2sh, redsh, W2f, bias2, Wout);
  __syncthreads();                              // #6

  if (tid < 32) {
    float t = 0.f;
#pragma unroll
    for (int w = 0; w < 8; ++w) t += redsh[tid][w];
    float x = fmlsh[32 + tid] + t;
    out[blk0 + 32 + tid] = 1.f / (1.f + expf(-x));
  }
}

// ---------------------------------------------------------------------------
extern "C" void kernel_launch(void* const* d_in, const int* in_sizes, int n_in,
                              void* d_out, int out_size, void* d_ws, size_t ws_size,
                              hipStream_t stream) {
  const int*   Xs   = (const int*)d_in[0];
  const float* Xd   = (const float*)d_in[1];
  const float* linW = (const float*)d_in[2];
  const float* fmW  = (const float*)d_in[3];
  const float* dW   = (const float*)d_in[4];
  const float* dB   = (const float*)d_in[5];
  const float* W1   = (const float*)d_in[6];
  const float* b1   = (const float*)d_in[7];
  const float* W2   = (const float*)d_in[8];
  const float* b2   = (const float*)d_in[9];
  const float* Wout = (const float*)d_in[10];
  float* out = (float*)d_out;

  char* ws = (char*)d_ws;
  __hip_bfloat16* W1f = (__hip_bfloat16*)(ws);             // 448*256*2 = 229,376
  __hip_bfloat16* W2f = (__hip_bfloat16*)(ws + 229376);    // 256*128*2 =  65,536

  convert_weights<<<384, 512, 0, stream>>>(W1, W2, W1f, W2f);
  deepfm_fused<<<BTOT / 64, 1024, 0, stream>>>(
      Xs, Xd, linW, fmW, dW, dB, W1f, b1, W2f, b2, Wout, out);
}

// Round 12
// 32.128 us; speedup vs baseline: 1.1262x; 1.1262x over previous
//
#include <hip/hip_runtime.h>
#include <hip/hip_bf16.h>
#include <math.h>

// Problem constants (DeepFM)
#define BTOT   16384
#define NF     26
#define VOCAB  100000
#define EDIM   16
#define DD     13
#define KPAD   448      // 429 padded to 14*32
#define KREAL  429
#define N1     256
#define N2     128
#define SPB    64       // samples per block
#define APAD   456      // A tile row stride (448+8)
#define H2PAD  264      // H2 tile row stride (256+8)

typedef __attribute__((ext_vector_type(8))) short bf16x8;
typedef __attribute__((ext_vector_type(4))) short bf16x4;
typedef __attribute__((ext_vector_type(4))) float f32x4;

static __device__ __forceinline__ bf16x8 ldb8(const __hip_bfloat16* p) {
  return *reinterpret_cast<const bf16x8*>(p);
}
static __device__ __forceinline__ short f2bf(float f) {
  __hip_bfloat16 h = __float2bfloat16(f);
  return *reinterpret_cast<short*>(&h);
}

// ---------------------------------------------------------------------------
// Kernel 1: repack weights -> bf16 B-fragment layout, coalesced reads.
//   W1  [256][429] f32 -> W1f[((k>>3)*256 + n)*8 + (k&7)]  (k padded to 448)
//   W2  [128][256] f32 -> W2f[((k>>3)*128 + n)*8 + (k&7)]
// ---------------------------------------------------------------------------
__global__ __launch_bounds__(512) void convert_weights(
    const float* __restrict__ W1, const float* __restrict__ W2,
    __hip_bfloat16* __restrict__ W1f, __hip_bfloat16* __restrict__ W2f) {
  const int bid = blockIdx.x;
  const int k = threadIdx.x;
  if (bid < 256) {
    const int n = bid;
    if (k < 448) {
      float v = (k < KREAL) ? W1[(size_t)n * KREAL + k] : 0.f;
      W1f[(((size_t)(k >> 3)) * N1 + n) * 8 + (k & 7)] = __float2bfloat16(v);
    }
  } else {
    const int n = bid - 256;
    if (k < 256) {
      float v = W2[(size_t)n * 256 + k];
      W2f[(((size_t)(k >> 3)) * N2 + n) * 8 + (k & 7)] = __float2bfloat16(v);
    }
  }
}

// ---------------------------------------------------------------------------
// Fused kernel, 1024 threads = 16 waves, 64 samples/block, grid 256 (1/CU).
// Phase 1: float4 embedding gather -> LDS A tile (bf16), FM linear+cross.
// Phase 2: GEMM1 (A[64,448] x W1f^T) +b1,ReLU -> LDS H2 tile.
// Phase 3: GEMM2 (H2[64,256] x W2f^T) +b2,ReLU, dot Wout.
// Phase 4: + fm logit, sigmoid -> out.
// ---------------------------------------------------------------------------
__global__ __launch_bounds__(1024, 4) void deepfm_fused(
    const int* __restrict__ Xs, const float* __restrict__ Xd,
    const float* __restrict__ linW, const float* __restrict__ fmW,
    const float* __restrict__ denseW, const float* __restrict__ denseB,
    const __hip_bfloat16* __restrict__ W1f, const float* __restrict__ b1,
    const __hip_bfloat16* __restrict__ W2f, const float* __restrict__ b2,
    const float* __restrict__ Wout, float* __restrict__ out) {

  __shared__ __hip_bfloat16 Ash[SPB][APAD];
  __shared__ __hip_bfloat16 H2sh[SPB][H2PAD];
  __shared__ float fmlsh[SPB];
  __shared__ float redsh[SPB][8];

  const int tid = threadIdx.x;
  const size_t blk0 = (size_t)blockIdx.x * SPB;

  // ---------------- phase 1: gather + FM ----------------
  {
    const int s   = tid >> 4;     // local sample 0..63
    const int sub = tid & 15;
    const int q   = sub & 3;      // e-quarter: dims q*4..q*4+3
    const int g   = sub >> 2;     // field group: fields g+4i
    const size_t b = blk0 + s;
    const int* xrow = Xs + b * NF;

    // prefetch indices (one dependent latency round)
    int idxs[7];
#pragma unroll
    for (int i = 0; i < 7; ++i) {
      int f = g + 4 * i;
      idxs[i] = (f < NF) ? xrow[f] : 0;
    }

    f32x4 sum = (f32x4){0.f, 0.f, 0.f, 0.f};
    f32x4 sumsq = (f32x4){0.f, 0.f, 0.f, 0.f};
    float part = 0.f;

#pragma unroll
    for (int i = 0; i < 7; ++i) {
      const int f = g + 4 * i;
      if (f < NF) {
        const float* row = fmW + ((size_t)f * VOCAB + idxs[i]) * EDIM;
        f32x4 v = *reinterpret_cast<const f32x4*>(row + q * 4);
        sum += v;
        sumsq += v * v;
        bf16x4 pk;
        pk[0] = f2bf(v[0]); pk[1] = f2bf(v[1]);
        pk[2] = f2bf(v[2]); pk[3] = f2bf(v[3]);
        *reinterpret_cast<bf16x4*>(&Ash[s][f * EDIM + q * 4]) = pk;
        if (q == (i & 3))
          part += linW[(size_t)f * VOCAB + idxs[i]];
      }
    }
    // reduce sum/sumsq over field-groups g (lanes xor 4, 8)
#pragma unroll
    for (int off = 4; off <= 8; off <<= 1) {
#pragma unroll
      for (int c = 0; c < 4; ++c) {
        sum[c] += __shfl_xor(sum[c], off);
        sumsq[c] += __shfl_xor(sumsq[c], off);
      }
    }
    if (g == 0) {                 // count each e-quarter's cross exactly once
      f32x4 c4 = sum * sum - sumsq;
      part += 0.5f * (c4[0] + c4[1] + c4[2] + c4[3]);
    }
    // dense features
    float xd = (sub < DD) ? Xd[b * DD + sub] : 0.f;
    Ash[s][416 + sub] = __float2bfloat16(xd);
    Ash[s][432 + sub] = __float2bfloat16(0.f);
    if (sub < DD) part += xd * denseW[sub];
    // reduce over the 16-lane group
#pragma unroll
    for (int off = 1; off < 16; off <<= 1)
      part += __shfl_xor(part, off);
    if (sub == 0) fmlsh[s] = part + denseB[0];
  }
  __syncthreads();

  // ---------------- phase 2: GEMM1 -> H2sh ----------------
  const int wave = tid >> 6;      // 0..15
  const int lane = tid & 63;
  const int lr = lane & 15;
  const int kg = lane >> 4;
  {
    const int n0 = wave * 16;     // 16 waves x 16 cols = 256
    f32x4 acc[4];
#pragma unroll
    for (int mt = 0; mt < 4; ++mt) acc[mt] = (f32x4){0.f, 0.f, 0.f, 0.f};

#pragma unroll
    for (int kt = 0; kt < KPAD / 32; ++kt) {
      const int kbase = kt * 32 + kg * 8;
      bf16x8 bf = ldb8(W1f + ((size_t)(kbase >> 3) * N1 + n0 + lr) * 8);
#pragma unroll
      for (int mt = 0; mt < 4; ++mt) {
        bf16x8 af = *reinterpret_cast<const bf16x8*>(&Ash[mt * 16 + lr][kbase]);
        acc[mt] = __builtin_amdgcn_mfma_f32_16x16x32_bf16(af, bf, acc[mt], 0, 0, 0);
      }
    }
    const int col = n0 + lr;
    const float bias = b1[col];
#pragma unroll
    for (int mt = 0; mt < 4; ++mt) {
#pragma unroll
      for (int r = 0; r < 4; ++r) {
        float v = acc[mt][r] + bias;
        v = v > 0.f ? v : 0.f;
        H2sh[mt * 16 + kg * 4 + r][col] = __float2bfloat16(v);
      }
    }
  }
  __syncthreads();

  // ---------------- phase 3: GEMM2 + Wout dot ----------------
  {
    const int c  = wave & 7;      // col-slice (16 cols)
    const int h  = wave >> 3;     // m-half (32 rows)
    const int n0 = c * 16;
    f32x4 acc[2];
    acc[0] = (f32x4){0.f, 0.f, 0.f, 0.f};
    acc[1] = (f32x4){0.f, 0.f, 0.f, 0.f};

#pragma unroll
    for (int kt = 0; kt < N1 / 32; ++kt) {
      const int kbase = kt * 32 + kg * 8;
      bf16x8 bf = ldb8(W2f + ((size_t)(kbase >> 3) * N2 + n0 + lr) * 8);
#pragma unroll
      for (int mt = 0; mt < 2; ++mt) {
        bf16x8 af = *reinterpret_cast<const bf16x8*>(&H2sh[h * 32 + mt * 16 + lr][kbase]);
        acc[mt] = __builtin_amdgcn_mfma_f32_16x16x32_bf16(af, bf, acc[mt], 0, 0, 0);
      }
    }
    const float w0 = Wout[n0 + lr];
    const float bb0 = b2[n0 + lr];
#pragma unroll
    for (int mt = 0; mt < 2; ++mt) {
#pragma unroll
      for (int r = 0; r < 4; ++r) {
        float v = acc[mt][r] + bb0;
        v = v > 0.f ? v : 0.f;
        v *= w0;
#pragma unroll
        for (int off = 1; off < 16; off <<= 1)
          v += __shfl_xor(v, off);
        if (lr == 0) redsh[h * 32 + mt * 16 + kg * 4 + r][c] = v;
      }
    }
  }
  __syncthreads();

  // ---------------- phase 4: combine + sigmoid ----------------
  if (tid < SPB) {
    const int row = tid;
    float t = 0.f;
#pragma unroll
    for (int w = 0; w < 8; ++w) t += redsh[row][w];
    float x = fmlsh[row] + t;
    out[blk0 + row] = 1.f / (1.f + expf(-x));
  }
}

// ---------------------------------------------------------------------------
extern "C" void kernel_launch(void* const* d_in, const int* in_sizes, int n_in,
                              void* d_out, int out_size, void* d_ws, size_t ws_size,
                              hipStream_t stream) {
  const int*   Xs   = (const int*)d_in[0];
  const float* Xd   = (const float*)d_in[1];
  const float* linW = (const float*)d_in[2];
  const float* fmW  = (const float*)d_in[3];
  const float* dW   = (const float*)d_in[4];
  const float* dB   = (const float*)d_in[5];
  const float* W1   = (const float*)d_in[6];
  const float* b1   = (const float*)d_in[7];
  const float* W2   = (const float*)d_in[8];
  const float* b2   = (const float*)d_in[9];
  const float* Wout = (const float*)d_in[10];
  float* out = (float*)d_out;

  char* ws = (char*)d_ws;
  __hip_bfloat16* W1f = (__hip_bfloat16*)(ws);             // 448*256*2 = 229,376
  __hip_bfloat16* W2f = (__hip_bfloat16*)(ws + 229376);    // 256*128*2 =  65,536

  convert_weights<<<384, 512, 0, stream>>>(W1, W2, W1f, W2f);
  deepfm_fused<<<BTOT / SPB, 1024, 0, stream>>>(
      Xs, Xd, linW, fmW, dW, dB, W1f, b1, W2f, b2, Wout, out);
}